// Round 4
// baseline (346.613 us; speedup 1.0000x reference)
//
#include <hip/hip_runtime.h>
#include <hip/hip_bf16.h>
#include <cstdint>
#include <cstddef>

// Problem constants (fixed by the reference)
#define TDIM 1024
#define HDIM 1024
#define FDIM 2048
#define NEXP 8
#define NENT 2048   // T * K

typedef __bf16 bf16_t;
typedef __bf16 bf16x4 __attribute__((ext_vector_type(4)));
typedef __bf16 bf16x8 __attribute__((ext_vector_type(8)));
typedef float  f32x4  __attribute__((ext_vector_type(4)));

#define H_ELEMS ((size_t)TDIM*HDIM)   // 1048576

// ---------------- workspace layout (bytes) ----------------
#define WB_OFFSETS 0                                   // int[16]
#define WB_ETOK    64
#define WB_ESCALE  (WB_ETOK + NENT*4)
#define WB_ACT     16512                               // bf16[NENT][FDIM] = 8 MB
#define WB_H       (WB_ACT + (size_t)NENT*FDIM*2)      // bf16[T][H] = 2 MB

__device__ __forceinline__ void gload16(const void* g, void* l) {
  __builtin_amdgcn_global_load_lds((const __attribute__((address_space(1))) void*)g,
                                   (__attribute__((address_space(3))) void*)l, 16, 0, 0);
}

// ---------------- routing (single block, one launch) ----------------
__global__ void route_all(const int* __restrict__ sel, const float* __restrict__ scal,
                          int* __restrict__ offsets, int* __restrict__ etok,
                          float* __restrict__ escale) {
  __shared__ int cnt[NEXP], cnt2[NEXP], offs[NEXP+1];
  const int t = threadIdx.x;    // 256 threads, 8 entries each
  if (t < NEXP) { cnt[t] = 0; cnt2[t] = 0; }
  __syncthreads();
  int e8[8];
  #pragma unroll
  for (int q = 0; q < 8; q++) {
    int i = t*8 + q;
    e8[q] = sel[i];
    atomicAdd(&cnt[e8[q]], 1);
  }
  __syncthreads();
  if (t == 0) {
    int s = 0;
    for (int e = 0; e < NEXP; e++) { offs[e] = s; offsets[e] = s; s += cnt[e]; }
    offs[NEXP] = s; offsets[NEXP] = s;
  }
  __syncthreads();
  #pragma unroll
  for (int q = 0; q < 8; q++) {
    int i = t*8 + q;
    int e = e8[q];
    int pos = offs[e] + atomicAdd(&cnt2[e], 1);
    etok[pos]   = i >> 1;       // TOPK == 2
    escale[pos] = scal[i];
  }
}

// ---------------- hidden fp32 -> bf16 (4 MB read, 2 MB write; L2-resident after) ----
__global__ void convert_h(const float* __restrict__ h, bf16_t* __restrict__ hbf) {
  size_t idx = ((size_t)blockIdx.x*256 + threadIdx.x) * 8;
  float4 v0 = ((const float4*)(h + idx))[0];
  float4 v1 = ((const float4*)(h + idx))[1];
  bf16x8 o;
  o[0]=(bf16_t)v0.x; o[1]=(bf16_t)v0.y; o[2]=(bf16_t)v0.z; o[3]=(bf16_t)v0.w;
  o[4]=(bf16_t)v1.x; o[5]=(bf16_t)v1.y; o[6]=(bf16_t)v1.z; o[7]=(bf16_t)v1.w;
  *(bf16x8*)(hbf + idx) = o;
}

// ---------------- grouped GEMMs: fp32 weights inline-converted, bf16 A via gload16 ----
// Tile 128(M) x 64(N) x 32(K), 512 threads = 8 waves as 4(m) x 2(n), wave tile 32x32.
// LDS A row = 32 bf16 = 4 segs of 16B; seg s of row r holds global seg s^(r&3)
// (swizzle applied on the gload16 SOURCE address; B writes apply it on the LDS address).

// GEMM1: act = silu(x@w1g^T + b1g) * (x@w1l^T + b1l)
__global__ __launch_bounds__(512, 4) void gemm1_v3(
    const bf16_t* __restrict__ hbf, const float* __restrict__ w1,
    const float* __restrict__ b1, const int* __restrict__ offsets,
    const int* __restrict__ etok, bf16_t* __restrict__ act)
{
  const int e   = blockIdx.z;
  const int off = offsets[e];
  const int nt  = offsets[e+1] - off;
  const int m0  = blockIdx.y * 128;
  if (m0 >= nt) return;
  const int n0  = blockIdx.x * 64;

  __shared__ __align__(16) bf16_t As[2][128*32];
  __shared__ __align__(16) bf16_t Bg[64*32];
  __shared__ __align__(16) bf16_t Bl[64*32];

  const int tid  = threadIdx.x;
  const int w    = tid >> 6, lane = tid & 63;
  const int quad = lane >> 4, lr = lane & 15;
  const int wm   = w >> 1,  wn = w & 1;

  // A loader: wave w stages rows [w*16, +16), lane covers row w*16+(lane>>2), seg lane&3
  const int ar   = w*16 + (lane >> 2);
  const int aseg = (lane & 3) ^ (ar & 3);           // swizzled global seg
  int ent = m0 + ar; if (ent > nt-1) ent = nt-1;    // clamp; masked in epilogue
  const int tok = etok[off + ent];
  const bf16_t* asrc = hbf + (size_t)tok*HDIM + aseg*8;
  bf16_t* adst[2] = { &As[0][w*512], &As[1][w*512] };

  // B loader: thread covers row tid>>3, 4 fp32 at col (tid&7)*4
  const int tr = tid >> 3, c4 = tid & 7;
  const float* gsrc = w1 + ((size_t)e*2*FDIM + (size_t)(n0 + tr))*HDIM + c4*4;
  const float* lsrc = gsrc + (size_t)FDIM*HDIM;
  const int bofs = tr*32 + (((c4 >> 1) ^ (tr & 3)) << 3) + (c4 & 1)*4;  // bf16 elems

  f32x4 accg[2][2] = {}, accl[2][2] = {};

  // prologue: stage k=0
  gload16(asrc, adst[0]);
  float4 g4 = *(const float4*)gsrc;
  float4 l4 = *(const float4*)lsrc;

  int p = 0;
  for (int k0 = 0; k0 < HDIM; k0 += 32, p ^= 1) {
    __syncthreads();      // A(k) gload16 done; prior MFMA frag reads done
    {
      bf16x4 v;
      v[0]=(bf16_t)g4.x; v[1]=(bf16_t)g4.y; v[2]=(bf16_t)g4.z; v[3]=(bf16_t)g4.w;
      *(bf16x4*)&Bg[bofs] = v;
      v[0]=(bf16_t)l4.x; v[1]=(bf16_t)l4.y; v[2]=(bf16_t)l4.z; v[3]=(bf16_t)l4.w;
      *(bf16x4*)&Bl[bofs] = v;
    }
    if (k0 + 32 < HDIM) {  // prefetch k+1
      gload16(asrc + k0 + 32, adst[p^1]);
      g4 = *(const float4*)(gsrc + k0 + 32);
      l4 = *(const float4*)(lsrc + k0 + 32);
    }
    __syncthreads();      // B(k) visible

    bf16x8 af[2], gf[2], lf[2];
    #pragma unroll
    for (int i = 0; i < 2; i++) {
      const int m = wm*32 + i*16 + lr;
      af[i] = *(const bf16x8*)&As[p][m*32 + ((quad ^ (m & 3)) << 3)];
    }
    #pragma unroll
    for (int j = 0; j < 2; j++) {
      const int n = wn*32 + j*16 + lr;
      gf[j] = *(const bf16x8*)&Bg[n*32 + ((quad ^ (n & 3)) << 3)];
      lf[j] = *(const bf16x8*)&Bl[n*32 + ((quad ^ (n & 3)) << 3)];
    }
    #pragma unroll
    for (int i = 0; i < 2; i++)
      #pragma unroll
      for (int j = 0; j < 2; j++) {
        accg[i][j] = __builtin_amdgcn_mfma_f32_16x16x32_bf16(af[i], gf[j], accg[i][j], 0, 0, 0);
        accl[i][j] = __builtin_amdgcn_mfma_f32_16x16x32_bf16(af[i], lf[j], accl[i][j], 0, 0, 0);
      }
  }

  // epilogue: bias + silu(gate)*lin -> act (bf16)
  #pragma unroll
  for (int j = 0; j < 2; j++) {
    const int f = n0 + wn*32 + j*16 + lr;
    const float bg_ = b1[e*2*FDIM + f];
    const float bl_ = b1[e*2*FDIM + FDIM + f];
    #pragma unroll
    for (int i = 0; i < 2; i++) {
      #pragma unroll
      for (int r = 0; r < 4; r++) {
        const int m = wm*32 + i*16 + quad*4 + r;
        if (m0 + m < nt) {
          const float g = accg[i][j][r] + bg_;
          const float l = accl[i][j][r] + bl_;
          const float s = g / (1.f + __expf(-g)) * l;
          act[(size_t)(off + m0 + m)*FDIM + f] = (bf16_t)s;
        }
      }
    }
  }
}

// GEMM2: y = act @ w2^T + b2; out[token] += scale * y  (atomic, split-K x2)
__global__ __launch_bounds__(512, 4) void gemm2_v3(
    const bf16_t* __restrict__ act, const float* __restrict__ w2,
    const float* __restrict__ b2, const int* __restrict__ offsets,
    const int* __restrict__ etok, const float* __restrict__ escale,
    float* __restrict__ out)
{
  const int e   = blockIdx.z;
  const int off = offsets[e];
  const int nt  = offsets[e+1] - off;
  const int m0  = blockIdx.y * 128;
  if (m0 >= nt) return;
  const int n0  = (blockIdx.x >> 1) * 64;
  const int kc  = blockIdx.x & 1;
  const int kbeg = kc * (FDIM/2);

  __shared__ __align__(16) bf16_t As[2][128*32];
  __shared__ __align__(16) bf16_t Bs[64*32];

  const int tid  = threadIdx.x;
  const int w    = tid >> 6, lane = tid & 63;
  const int quad = lane >> 4, lr = lane & 15;
  const int wm   = w >> 1,  wn = w & 1;

  const int ar   = w*16 + (lane >> 2);
  const int aseg = (lane & 3) ^ (ar & 3);
  int ent = m0 + ar; if (ent > nt-1) ent = nt-1;
  const bf16_t* asrc = act + (size_t)(off + ent)*FDIM + kbeg + aseg*8;
  bf16_t* adst[2] = { &As[0][w*512], &As[1][w*512] };

  const int tr = tid >> 3, c4 = tid & 7;
  const float* bsrc = w2 + ((size_t)e*HDIM + (size_t)(n0 + tr))*FDIM + kbeg + c4*4;
  const int bofs = tr*32 + (((c4 >> 1) ^ (tr & 3)) << 3) + (c4 & 1)*4;

  f32x4 acc[2][2] = {};

  gload16(asrc, adst[0]);
  float4 b4 = *(const float4*)bsrc;

  int p = 0;
  for (int k0 = 0; k0 < FDIM/2; k0 += 32, p ^= 1) {
    __syncthreads();
    {
      bf16x4 v;
      v[0]=(bf16_t)b4.x; v[1]=(bf16_t)b4.y; v[2]=(bf16_t)b4.z; v[3]=(bf16_t)b4.w;
      *(bf16x4*)&Bs[bofs] = v;
    }
    if (k0 + 32 < FDIM/2) {
      gload16(asrc + k0 + 32, adst[p^1]);
      b4 = *(const float4*)(bsrc + k0 + 32);
    }
    __syncthreads();

    bf16x8 af[2], bfr[2];
    #pragma unroll
    for (int i = 0; i < 2; i++) {
      const int m = wm*32 + i*16 + lr;
      af[i] = *(const bf16x8*)&As[p][m*32 + ((quad ^ (m & 3)) << 3)];
    }
    #pragma unroll
    for (int j = 0; j < 2; j++) {
      const int n = wn*32 + j*16 + lr;
      bfr[j] = *(const bf16x8*)&Bs[n*32 + ((quad ^ (n & 3)) << 3)];
    }
    #pragma unroll
    for (int i = 0; i < 2; i++)
      #pragma unroll
      for (int j = 0; j < 2; j++)
        acc[i][j] = __builtin_amdgcn_mfma_f32_16x16x32_bf16(af[i], bfr[j], acc[i][j], 0, 0, 0);
  }

  // epilogue: + b2 (k-chunk 0 only), scale, atomic scatter-add
  #pragma unroll
  for (int i = 0; i < 2; i++) {
    #pragma unroll
    for (int r = 0; r < 4; r++) {
      const int m = wm*32 + i*16 + quad*4 + r;
      if (m0 + m < nt) {
        const int slot = off + m0 + m;
        const int t    = etok[slot];
        const float s  = escale[slot];
        #pragma unroll
        for (int j = 0; j < 2; j++) {
          const int n = n0 + wn*32 + j*16 + lr;
          float v = acc[i][j][r];
          if (kc == 0) v += b2[e*HDIM + n];
          atomicAdd(&out[(size_t)t*HDIM + n], s * v);
        }
      }
    }
  }
}

extern "C" void kernel_launch(void* const* d_in, const int* in_sizes, int n_in,
                              void* d_out, int out_size, void* d_ws, size_t ws_size,
                              hipStream_t stream) {
  const float* hidden = (const float*)d_in[0];
  const int*   sel    = (const int*)d_in[1];
  const float* scal   = (const float*)d_in[2];
  const float* w1     = (const float*)d_in[3];
  const float* b1     = (const float*)d_in[4];
  const float* w2     = (const float*)d_in[5];
  const float* b2     = (const float*)d_in[6];
  float* out = (float*)d_out;

  char* ws = (char*)d_ws;
  int*    offsets = (int*)(ws + WB_OFFSETS);
  int*    etok    = (int*)(ws + WB_ETOK);
  float*  escale  = (float*)(ws + WB_ESCALE);
  bf16_t* act     = (bf16_t*)(ws + WB_ACT);
  bf16_t* hbf     = (bf16_t*)(ws + WB_H);

  hipMemsetAsync(d_out, 0, (size_t)out_size * sizeof(float), stream);

  route_all<<<1, 256, 0, stream>>>(sel, scal, offsets, etok, escale);
  convert_h<<<(int)(H_ELEMS/8/256), 256, 0, stream>>>(hidden, hbf);

  // gemm1: x = n-tile (32), y = m-tile (16, most early-exit), z = expert.
  // m-tiles of the same (e,n) differ by 32 in linear block id -> same XCD -> w1 L2-shared.
  gemm1_v3<<<dim3(FDIM/64, NENT/128, NEXP), 512, 0, stream>>>(hbf, w1, b1, offsets, etok, act);
  // gemm2: x = n-tile(16) x splitK(2), y = m-tile, z = expert.
  gemm2_v3<<<dim3((HDIM/64)*2, NENT/128, NEXP), 512, 0, stream>>>(act, w2, b2, offsets, etok, escale, out);
}